// Round 3
// baseline (35.711 us; speedup 1.0000x reference)
//
#include <hip/hip_runtime.h>

// OKLab -> ACEScg: per-pixel 3-vector transform on [B=8, C=3, H=1024, W=1024] fp32.
// Memory-bound: ~201 MB total traffic, roofline ~32 us @ 6.3 TB/s.
// R2: same as R1 (NT stores + 2 quads/thread) with ext_vector reference-binding
//     compile fix (return struct by value, assign elements).

#define HW (1024 * 1024)
#define QP (HW / 4)                 // float4 quads per plane = 2^18
#define NQUADS (8 * QP)             // total pixel-quads = 2^21
#define NTHREADS (NQUADS / 2)       // 2 quads per thread = 2^20

typedef float f4 __attribute__((ext_vector_type(4)));

struct Px { float r, g, b; };

__device__ __forceinline__ Px oklab_px(float L, float A, float Bv) {
    // y = x @ M1  (row-vector: y_j = sum_i x_i * M1[i][j])
    float y0 = fmaf(0.2158037573f,  Bv, fmaf(0.3963377774f,  A, L));
    float y1 = fmaf(-0.0638541728f, Bv, fmaf(-0.1055613458f, A, L));
    float y2 = fmaf(-1.291485548f,  Bv, fmaf(-0.0894841775f, A, L));

    // signed cube == plain cube
    float l = y0 * y0 * y0;
    float m = y1 * y1 * y1;
    float s = y2 * y2 * y2;

    // z = y @ M2
    float z0 = fmaf(0.2309699292f, s, fmaf(-3.3077115913f, m, 4.0767416621f  * l));
    float z1 = fmaf(-0.3413193965f, s, fmaf(2.6097574011f,  m, -1.2684380046f * l));
    float z2 = fmaf(1.707614701f,  s, fmaf(-0.7034186147f, m, 0.0041960863f  * l));

    // w = z @ M3
    Px p;
    p.r = fmaf(0.0474050234857193f, z2, fmaf(0.339523761133735f,  z1, 0.613130111351449f  * z0));
    p.g = fmaf(0.0134571284251877f, z2, fmaf(0.916356903394254f,  z1, 0.0701050973342151f * z0));
    p.b = fmaf(0.869782709459968f,  z2, fmaf(0.109559786350199f,  z1, 0.0205851228833001f * z0));
    return p;
}

__device__ __forceinline__ void do_quad(f4 xL, f4 xA, f4 xB,
                                        f4& oR, f4& oG, f4& oB) {
    Px p0 = oklab_px(xL.x, xA.x, xB.x);
    Px p1 = oklab_px(xL.y, xA.y, xB.y);
    Px p2 = oklab_px(xL.z, xA.z, xB.z);
    Px p3 = oklab_px(xL.w, xA.w, xB.w);
    oR.x = p0.r; oR.y = p1.r; oR.z = p2.r; oR.w = p3.r;
    oG.x = p0.g; oG.y = p1.g; oG.z = p2.g; oG.w = p3.g;
    oB.x = p0.b; oB.y = p1.b; oB.z = p2.b; oB.w = p3.b;
}

__global__ __launch_bounds__(256) void oklab_to_acescg_kernel(
    const f4* __restrict__ in, f4* __restrict__ out) {
    int t0 = blockIdx.x * blockDim.x + threadIdx.x;   // 0 .. 2^20-1
    int t1 = t0 + NTHREADS;                            // second quad, far half

    int b0 = t0 >> 18, q0 = t0 & (QP - 1);
    int b1 = t1 >> 18, q1 = t1 & (QP - 1);

    // Issue all 6 loads before any dependent math (MLP).
    const f4 aL = in[(b0 * 3 + 0) * QP + q0];
    const f4 aA = in[(b0 * 3 + 1) * QP + q0];
    const f4 aB = in[(b0 * 3 + 2) * QP + q0];
    const f4 cL = in[(b1 * 3 + 0) * QP + q1];
    const f4 cA = in[(b1 * 3 + 1) * QP + q1];
    const f4 cB = in[(b1 * 3 + 2) * QP + q1];

    f4 aR, aG, aBo, cR, cG, cBo;
    do_quad(aL, aA, aB, aR, aG, aBo);
    do_quad(cL, cA, cB, cR, cG, cBo);

    // Streaming output: non-temporal stores, don't pollute L2/L3.
    __builtin_nontemporal_store(aR,  &out[(b0 * 3 + 0) * QP + q0]);
    __builtin_nontemporal_store(aG,  &out[(b0 * 3 + 1) * QP + q0]);
    __builtin_nontemporal_store(aBo, &out[(b0 * 3 + 2) * QP + q0]);
    __builtin_nontemporal_store(cR,  &out[(b1 * 3 + 0) * QP + q1]);
    __builtin_nontemporal_store(cG,  &out[(b1 * 3 + 1) * QP + q1]);
    __builtin_nontemporal_store(cBo, &out[(b1 * 3 + 2) * QP + q1]);
}

extern "C" void kernel_launch(void* const* d_in, const int* in_sizes, int n_in,
                              void* d_out, int out_size, void* d_ws, size_t ws_size,
                              hipStream_t stream) {
    const f4* in = (const f4*)d_in[0];
    f4* out = (f4*)d_out;
    int threads = 256;
    int blocks = NTHREADS / threads;   // 4096 blocks, exact coverage
    oklab_to_acescg_kernel<<<blocks, threads, 0, stream>>>(in, out);
}